// Round 1
// baseline (678.662 us; speedup 1.0000x reference)
//
#include <hip/hip_runtime.h>
#include <hip/hip_bf16.h>

// ---------------- problem dims ----------------
constexpr int T_ = 2048;   // B*S tokens
constexpr int H_ = 2048;
constexpr int F_ = 1408;
constexpr int E_ = 8;
constexpr int SF_ = 2816;  // shared intermediate

typedef __bf16 bf16;
typedef bf16 bf16x8 __attribute__((ext_vector_type(8)));
typedef float f32x4 __attribute__((ext_vector_type(4)));

#define DEVI __device__ __forceinline__

// async global->LDS, 16B per lane. LDS dest must be wave-uniform base + lane*16
// (our linear chunk mapping guarantees that).
DEVI void async16(const void* g, void* l) {
    __builtin_amdgcn_global_load_lds(
        (const __attribute__((address_space(1))) unsigned int*)g,
        (__attribute__((address_space(3))) unsigned int*)l, 16, 0, 0);
}

// ---------------- transpose + fp32->bf16 convert ----------------
// src [z][R][C] fp32  ->  dst [z][C][R] bf16
__global__ void transpose_cvt(const float* __restrict__ src, bf16* __restrict__ dst,
                              int R, int C) {
    int z = blockIdx.z;
    src += (size_t)z * R * C;
    dst += (size_t)z * R * C;
    __shared__ float tile[32][33];
    int tx = threadIdx.x, ty = threadIdx.y;  // 32 x 8
    int c0 = blockIdx.x * 32, r0 = blockIdx.y * 32;
#pragma unroll
    for (int i = 0; i < 4; i++)
        tile[ty + i * 8][tx] = src[(size_t)(r0 + ty + i * 8) * C + c0 + tx];
    __syncthreads();
#pragma unroll
    for (int i = 0; i < 4; i++)
        dst[(size_t)(c0 + ty + i * 8) * R + r0 + tx] = (bf16)tile[tx][ty + i * 8];
}

// ---------------- x fp32 -> bf16 ----------------
__global__ void convert_x(const float* __restrict__ x, bf16* __restrict__ xb) {
    int i = (blockIdx.x * 256 + threadIdx.x) * 8;
    float4 a = *(const float4*)(x + i);
    float4 b = *(const float4*)(x + i + 4);
    bf16x8 v;
    v[0] = (bf16)a.x; v[1] = (bf16)a.y; v[2] = (bf16)a.z; v[3] = (bf16)a.w;
    v[4] = (bf16)b.x; v[5] = (bf16)b.y; v[6] = (bf16)b.z; v[7] = (bf16)b.w;
    *(bf16x8*)(xb + i) = v;
}

// ---------------- gate: softmax + top-2 routing ----------------
__global__ void gate_route(const float* __restrict__ x, const float* __restrict__ gw,
                           int* __restrict__ cnt, int* __restrict__ list,
                           float* __restrict__ wlist) {
    int t = blockIdx.x;
    int tid = threadIdx.x;
    float p[E_];
#pragma unroll
    for (int e = 0; e < E_; e++) p[e] = 0.f;
    const float* xr = x + (size_t)t * H_;
    for (int h = tid; h < H_; h += 256) {
        float xv = xr[h];
#pragma unroll
        for (int e = 0; e < E_; e++) p[e] += xv * gw[e * H_ + h];
    }
#pragma unroll
    for (int e = 0; e < E_; e++)
#pragma unroll
        for (int off = 32; off > 0; off >>= 1) p[e] += __shfl_down(p[e], off, 64);
    __shared__ float wred[4][E_];
    int lane = tid & 63, wid = tid >> 6;
    if (lane == 0)
#pragma unroll
        for (int e = 0; e < E_; e++) wred[wid][e] = p[e];
    __syncthreads();
    if (tid == 0) {
        float l[E_];
#pragma unroll
        for (int e = 0; e < E_; e++) l[e] = wred[0][e] + wred[1][e] + wred[2][e] + wred[3][e];
        float mx = l[0];
#pragma unroll
        for (int e = 1; e < E_; e++) mx = fmaxf(mx, l[e]);
        float sc[E_], s = 0.f;
#pragma unroll
        for (int e = 0; e < E_; e++) { sc[e] = __expf(l[e] - mx); s += sc[e]; }
#pragma unroll
        for (int e = 0; e < E_; e++) sc[e] /= s;
        int i1 = 0;
#pragma unroll
        for (int e = 1; e < E_; e++) if (sc[e] > sc[i1]) i1 = e;
        int i2 = (i1 == 0) ? 1 : 0;
#pragma unroll
        for (int e = 0; e < E_; e++) if (e != i1 && sc[e] > sc[i2]) i2 = e;
        int p1 = atomicAdd(&cnt[i1], 1);
        list[i1 * T_ + p1] = t; wlist[i1 * T_ + p1] = sc[i1];
        int p2 = atomicAdd(&cnt[i2], 1);
        list[i2 * T_ + p2] = t; wlist[i2 * T_ + p2] = sc[i2];
    }
}

// ---------------- gather routed rows (bf16) ----------------
__global__ void gather_rows(const bf16* __restrict__ xb, const int* __restrict__ cnt,
                            const int* __restrict__ list, bf16* __restrict__ xA) {
    int i = blockIdx.x, e = blockIdx.y;
    if (i >= cnt[e]) return;
    int t = list[e * T_ + i];
    const float4* s = (const float4*)(xb + (size_t)t * H_);
    float4* d = (float4*)(xA + ((size_t)e * T_ + i) * H_);
    d[threadIdx.x] = s[threadIdx.x];
}

// ---------------- GEMM: C_act = silu(A@Bg^T) * (A@Bu^T), bf16 out ----------------
// A [rows][K] bf16 (compact), Bg/Bu [N][K] bf16. BM=128 BN=64 BK=64, 256 thr.
__global__ void gemm_dual(const bf16* __restrict__ A, const bf16* __restrict__ Bg,
                          const bf16* __restrict__ Bu, bf16* __restrict__ Cact,
                          const int* __restrict__ cntPtr, int Mfull, int K, int N,
                          long sAe, long sBe, long sCe) {
    int e = blockIdx.z;
    A += (size_t)e * sAe; Bg += (size_t)e * sBe; Bu += (size_t)e * sBe;
    Cact += (size_t)e * sCe;
    int M = cntPtr ? cntPtr[e] : Mfull;
    int row0 = blockIdx.y * 128;
    if (row0 >= M) return;
    int col0 = blockIdx.x * 64;

    __shared__ __align__(16) bf16 As[128 * 64];
    __shared__ __align__(16) bf16 Bgs[64 * 64];
    __shared__ __align__(16) bf16 Bus[64 * 64];

    int tid = threadIdx.x, lane = tid & 63, wid = tid >> 6;
    int wm = (wid >> 1) * 64, wn = (wid & 1) * 32;
    int lm = lane & 15, lq = lane >> 4;

    f32x4 accg[4][2] = {};
    f32x4 accu[4][2] = {};

    int nkt = K >> 6;
    for (int kt = 0; kt < nkt; kt++) {
        int k0 = kt * 64;
#pragma unroll
        for (int j = 0; j < 4; j++) {          // A tile: 1024 16B chunks
            int L = j * 256 + tid;
            int m = L >> 3, cp = L & 7, c = cp ^ (m & 7);
            int gr = row0 + m; if (gr >= M) gr = M - 1;
            async16(A + (size_t)gr * K + k0 + c * 8, (void*)(As + L * 8));
        }
#pragma unroll
        for (int j = 0; j < 2; j++) {          // Bg/Bu tiles: 512 chunks each
            int L = j * 256 + tid;
            int n = L >> 3, cp = L & 7, c = cp ^ (n & 7);
            async16(Bg + (size_t)(col0 + n) * K + k0 + c * 8, (void*)(Bgs + L * 8));
            async16(Bu + (size_t)(col0 + n) * K + k0 + c * 8, (void*)(Bus + L * 8));
        }
        __syncthreads();
#pragma unroll
        for (int kk = 0; kk < 2; kk++) {
            bf16x8 af[4], bgf[2], buf_[2];
            int cc = kk * 4 + lq;
#pragma unroll
            for (int mi = 0; mi < 4; mi++) {
                int r = wm + mi * 16 + lm;
                af[mi] = *(const bf16x8*)(As + r * 64 + ((cc ^ (r & 7)) * 8));
            }
#pragma unroll
            for (int ni = 0; ni < 2; ni++) {
                int r = wn + ni * 16 + lm;
                bgf[ni]  = *(const bf16x8*)(Bgs + r * 64 + ((cc ^ (r & 7)) * 8));
                buf_[ni] = *(const bf16x8*)(Bus + r * 64 + ((cc ^ (r & 7)) * 8));
            }
#pragma unroll
            for (int mi = 0; mi < 4; mi++)
#pragma unroll
                for (int ni = 0; ni < 2; ni++) {
                    accg[mi][ni] = __builtin_amdgcn_mfma_f32_16x16x32_bf16(af[mi], bgf[ni], accg[mi][ni], 0, 0, 0);
                    accu[mi][ni] = __builtin_amdgcn_mfma_f32_16x16x32_bf16(af[mi], buf_[ni], accu[mi][ni], 0, 0, 0);
                }
        }
        __syncthreads();
    }
    // epilogue: silu(g)*u -> bf16
#pragma unroll
    for (int mi = 0; mi < 4; mi++)
#pragma unroll
        for (int r = 0; r < 4; r++) {
            int gr = row0 + wm + mi * 16 + lq * 4 + r;
            if (gr >= M) continue;
#pragma unroll
            for (int ni = 0; ni < 2; ni++) {
                int gc = col0 + wn + ni * 16 + lm;
                float g = accg[mi][ni][r], u = accu[mi][ni][r];
                float act = g / (1.f + __expf(-g)) * u;
                Cact[(size_t)gr * N + gc] = (bf16)act;
            }
        }
}

// ---------------- GEMM: Out = A@Bt^T, fp32 out (write or weighted atomic add) ----
// A [rows][K] bf16, Bt [N][K] bf16. BM=128 BN=128 BK=64, 256 thr.
__global__ void gemm_single(const bf16* __restrict__ A, const bf16* __restrict__ Bt,
                            float* __restrict__ Out, const int* __restrict__ cntPtr,
                            int Mfull, int K, int N, const int* __restrict__ list,
                            const float* __restrict__ wlist, long sAe, long sBe) {
    int e = blockIdx.z;
    A += (size_t)e * sAe; Bt += (size_t)e * sBe;
    const int* lst = list ? list + (size_t)e * T_ : nullptr;
    const float* wl = wlist ? wlist + (size_t)e * T_ : nullptr;
    int M = cntPtr ? cntPtr[e] : Mfull;
    int row0 = blockIdx.y * 128;
    if (row0 >= M) return;
    int col0 = blockIdx.x * 128;

    __shared__ __align__(16) bf16 As[128 * 64];
    __shared__ __align__(16) bf16 Bs[128 * 64];

    int tid = threadIdx.x, lane = tid & 63, wid = tid >> 6;
    int wm = (wid >> 1) * 64, wn = (wid & 1) * 64;
    int lm = lane & 15, lq = lane >> 4;

    f32x4 acc[4][4] = {};
    int nkt = K >> 6;
    for (int kt = 0; kt < nkt; kt++) {
        int k0 = kt * 64;
#pragma unroll
        for (int j = 0; j < 4; j++) {
            int L = j * 256 + tid;
            int m = L >> 3, cp = L & 7, c = cp ^ (m & 7);
            int gr = row0 + m; if (gr >= M) gr = M - 1;
            async16(A + (size_t)gr * K + k0 + c * 8, (void*)(As + L * 8));
            async16(Bt + (size_t)(col0 + m) * K + k0 + c * 8, (void*)(Bs + L * 8));
        }
        __syncthreads();
#pragma unroll
        for (int kk = 0; kk < 2; kk++) {
            bf16x8 af[4], bfr[4];
            int cc = kk * 4 + lq;
#pragma unroll
            for (int i = 0; i < 4; i++) {
                int ra = wm + i * 16 + lm;
                af[i] = *(const bf16x8*)(As + ra * 64 + ((cc ^ (ra & 7)) * 8));
                int rb = wn + i * 16 + lm;
                bfr[i] = *(const bf16x8*)(Bs + rb * 64 + ((cc ^ (rb & 7)) * 8));
            }
#pragma unroll
            for (int mi = 0; mi < 4; mi++)
#pragma unroll
                for (int ni = 0; ni < 4; ni++)
                    acc[mi][ni] = __builtin_amdgcn_mfma_f32_16x16x32_bf16(af[mi], bfr[ni], acc[mi][ni], 0, 0, 0);
        }
        __syncthreads();
    }
#pragma unroll
    for (int mi = 0; mi < 4; mi++)
#pragma unroll
        for (int r = 0; r < 4; r++) {
            int cr = row0 + wm + mi * 16 + lq * 4 + r;
            if (cr >= M) continue;
            if (lst) {
                int t = lst[cr];
                float w = wl[cr];
#pragma unroll
                for (int ni = 0; ni < 4; ni++) {
                    int gc = col0 + wn + ni * 16 + lm;
                    atomicAdd(&Out[(size_t)t * N + gc], w * acc[mi][ni][r]);
                }
            } else {
#pragma unroll
                for (int ni = 0; ni < 4; ni++) {
                    int gc = col0 + wn + ni * 16 + lm;
                    Out[(size_t)cr * N + gc] = acc[mi][ni][r];
                }
            }
        }
}

// ---------------- launch ----------------
extern "C" void kernel_launch(void* const* d_in, const int* in_sizes, int n_in,
                              void* d_out, int out_size, void* d_ws, size_t ws_size,
                              hipStream_t stream) {
    const float* x     = (const float*)d_in[0];
    const float* gw    = (const float*)d_in[1];
    const float* gproj = (const float*)d_in[2];
    const float* uproj = (const float*)d_in[3];
    const float* dproj = (const float*)d_in[4];
    const float* sg    = (const float*)d_in[5];
    const float* su    = (const float*)d_in[6];
    const float* sd    = (const float*)d_in[7];
    float* out = (float*)d_out;

    char* w = (char*)d_ws;
    size_t off = 0;
    auto alloc = [&](size_t bytes) { void* p = w + off; off += (bytes + 255) & ~(size_t)255; return p; };
    bf16* wg_t   = (bf16*)alloc((size_t)E_ * F_ * H_ * 2);   // [E][F][H]
    bf16* wu_t   = (bf16*)alloc((size_t)E_ * F_ * H_ * 2);   // [E][F][H]
    bf16* wd_t   = (bf16*)alloc((size_t)E_ * H_ * F_ * 2);   // [E][H][F]
    bf16* sg_t   = (bf16*)alloc((size_t)SF_ * H_ * 2);       // [SF][H]
    bf16* su_t   = (bf16*)alloc((size_t)SF_ * H_ * 2);       // [SF][H]
    bf16* sd_t   = (bf16*)alloc((size_t)H_ * SF_ * 2);       // [H][SF]
    bf16* xb     = (bf16*)alloc((size_t)T_ * H_ * 2);        // [T][H]
    bf16* xA     = (bf16*)alloc((size_t)E_ * T_ * H_ * 2);   // [E][T][H] gathered
    bf16* act    = (bf16*)alloc((size_t)E_ * T_ * F_ * 2);   // [E][T][F]
    bf16* act_sh = (bf16*)alloc((size_t)T_ * SF_ * 2);       // [T][SF]
    int*  cnt    = (int*)alloc(256);
    int*  list   = (int*)alloc((size_t)E_ * T_ * 4);
    float* wlist = (float*)alloc((size_t)E_ * T_ * 4);
    (void)ws_size; (void)in_sizes; (void)n_in; (void)out_size;

    hipMemsetAsync(cnt, 0, 256, stream);

    dim3 tb(32, 8);
    transpose_cvt<<<dim3(F_ / 32, H_ / 32, E_), tb, 0, stream>>>(gproj, wg_t, H_, F_);
    transpose_cvt<<<dim3(F_ / 32, H_ / 32, E_), tb, 0, stream>>>(uproj, wu_t, H_, F_);
    transpose_cvt<<<dim3(H_ / 32, F_ / 32, E_), tb, 0, stream>>>(dproj, wd_t, F_, H_);
    transpose_cvt<<<dim3(SF_ / 32, H_ / 32, 1), tb, 0, stream>>>(sg, sg_t, H_, SF_);
    transpose_cvt<<<dim3(SF_ / 32, H_ / 32, 1), tb, 0, stream>>>(su, su_t, H_, SF_);
    transpose_cvt<<<dim3(H_ / 32, SF_ / 32, 1), tb, 0, stream>>>(sd, sd_t, SF_, H_);

    convert_x<<<T_ * H_ / (256 * 8), 256, 0, stream>>>(x, xb);
    gate_route<<<T_, 256, 0, stream>>>(x, gw, cnt, list, wlist);
    gather_rows<<<dim3(T_, E_), 256, 0, stream>>>(xb, cnt, list, xA);

    // experts: act = silu(x@gate^T)*(x@up^T)
    gemm_dual<<<dim3(F_ / 64, T_ / 128, E_), 256, 0, stream>>>(
        xA, wg_t, wu_t, act, cnt, T_, H_, F_,
        (long)T_ * H_, (long)F_ * H_, (long)T_ * F_);
    // shared: act_sh = silu(x@sg)*(x@su)
    gemm_dual<<<dim3(SF_ / 64, T_ / 128, 1), 256, 0, stream>>>(
        xb, sg_t, su_t, act_sh, nullptr, T_, H_, SF_, 0, 0, 0);
    // shared down: out = act_sh @ shared_down   (full write, establishes out)
    gemm_single<<<dim3(H_ / 128, T_ / 128, 1), 256, 0, stream>>>(
        act_sh, sd_t, out, nullptr, T_, SF_, H_, nullptr, nullptr, 0, 0);
    // experts down: out += w * act @ down^T (atomic scatter)
    gemm_single<<<dim3(H_ / 128, T_ / 128, E_), 256, 0, stream>>>(
        act, wd_t, out, cnt, T_, F_, H_, list, wlist,
        (long)T_ * F_, (long)H_ * F_);
}